// Round 6
// baseline (468.734 us; speedup 1.0000x reference)
//
#include <hip/hip_runtime.h>
#include <hip/hip_cooperative_groups.h>
#include <math.h>

namespace cg = cooperative_groups;

#define N_NODES 20000
#define N_EDGES 320000
#define IN_F 256
#define OUT_F 64
#define HEADS 4
#define NCOL 256            // HEADS*OUT_F
#define LRELU_ALPHA 0.1f
#define ELL_CAP 64          // max degree capacity; P(overflow) < 1e-13

#define FUSED_BLOCKS 512                   // 2 blocks/CU exactly (LDS-limited)
#define FUSED_THREADS 512

// fallback (round-5 verified path) sizes
#define SCAT_X 313
#define GEMM_GB 157

typedef __attribute__((ext_vector_type(8))) short short8;
typedef __attribute__((ext_vector_type(4))) float floatx4;

__device__ __forceinline__ float lrelu(float x) {
    return x > 0.f ? x : LRELU_ALPHA * x;
}
__device__ __forceinline__ unsigned short f2bf(float f) {   // RNE f32->bf16
    unsigned int u = __float_as_uint(f);
    u = (u + 0x7FFF + ((u >> 16) & 1)) >> 16;
    return (unsigned short)u;
}
__device__ __forceinline__ float bf2f(unsigned short u) {
    return __uint_as_float(((unsigned int)u) << 16);
}

// ===========================================================================
// FUSED cooperative kernel: P0 prep -> sync -> P1 scatter+GEMM -> sync -> P2 agg
// All phase bodies are ports of the round-5 verified kernels.
// ===========================================================================
__global__ __launch_bounds__(512, 4) void fused_kernel(
    const float* __restrict__ A0, const float* __restrict__ A1,
    const float* __restrict__ Ws, const float* __restrict__ Wt,
    const float* __restrict__ a1, const float* __restrict__ a2,
    const int* __restrict__ src, const int* __restrict__ tgt,
    unsigned short* __restrict__ Wsb, unsigned short* __restrict__ Wtb,
    unsigned short* __restrict__ C0, unsigned short* __restrict__ C1,
    float* __restrict__ ss1, float* __restrict__ ss2,
    float* __restrict__ tt1, float* __restrict__ tt2,
    int* __restrict__ cnt_t, int* __restrict__ cnt_s,
    unsigned short* __restrict__ elist_t, unsigned short* __restrict__ elist_s,
    float* __restrict__ h_st, float* __restrict__ h_ts)
{
    cg::grid_group grid = cg::this_grid();
    const int tid = threadIdx.x;
    const int blk = blockIdx.x;              // 0..511
    const int gid = blk * FUSED_THREADS + tid;

    __shared__ __align__(16) unsigned short Bl[128][264];   // 67,584 B

    // ---------------- P0: zero ELL counters + W convert --------------------
    if (gid < 2 * N_NODES) cnt_t[gid] = 0;   // cnt_t, cnt_s contiguous
    if (gid < 16384) {
        const int mat = gid >> 13;
        const int r   = gid & 8191;
        const int kc  = r >> 8;              // 0..31 (k-octet)
        const int c   = r & 255;
        const float* W    = mat ? Wt : Ws;
        unsigned short* O = mat ? Wtb : Wsb;
        const int h = c >> 6, j = c & 63;
        const int k0 = kc * 8;
        unsigned short v[8] __attribute__((aligned(16)));
#pragma unroll
        for (int i = 0; i < 8; ++i)
            v[i] = f2bf(W[(size_t)h * (IN_F * OUT_F) + (size_t)(k0 + i) * OUT_F + j]);
        *(uint4*)(O + (size_t)c * IN_F + k0) = *(const uint4*)v;
    }

    grid.sync();

    // ---------------- P1a: ELL scatter (grid-stride, <=2 edges/thread) ----
    for (int e = gid; e < N_EDGES; e += FUSED_BLOCKS * FUSED_THREADS) {
        const int s = src[e], t = tgt[e];
        const int p = atomicAdd(&cnt_t[t], 1);
        const int q = atomicAdd(&cnt_s[s], 1);
        if (p < ELL_CAP) elist_t[t * ELL_CAP + p] = (unsigned short)s;
        if (q < ELL_CAP) elist_s[s * ELL_CAP + q] = (unsigned short)t;
    }

    // ---------------- P1b: half-W-resident GEMM + fused dots ---------------
    {
        const int y    = blk >> 8;           // direction 0/1
        const int half = (blk >> 7) & 1;
        const int bi   = blk & 127;          // 0..127
        const float* A           = y ? A1 : A0;
        const unsigned short* Wb = y ? Wtb : Wsb;
        unsigned short* C        = y ? C1 : C0;

        for (int i = tid; i < 4096; i += 512) {
            const int n  = i >> 5;           // 0..127
            const int kc = (i & 31) << 3;    // k-offset in shorts
            *(uint4*)&Bl[n][kc] = *(const uint4*)(Wb + (size_t)(half * 128 + n) * IN_F + kc);
        }
        __syncthreads();

        const int lane = tid & 63;
        const int w    = tid >> 6;           // wave 0..7
        const int quad = lane >> 4;
        const int l15  = lane & 15;

        const int off_aj = y ? 64 : 0;
        float* o1 = y ? tt1 : ss1;
        float* o2 = y ? tt2 : ss2;

        for (int g = bi * 8 + w; g < 1250; g += 1024) {
            const float* arow = A + (size_t)(g * 16 + l15) * IN_F + quad * 8;

            // batch 1: kk = 0..3
            float4 ua[8];
#pragma unroll
            for (int kk = 0; kk < 4; ++kk) {
                ua[2 * kk]     = *(const float4*)(arow + kk * 32);
                ua[2 * kk + 1] = *(const float4*)(arow + kk * 32 + 4);
            }
            short8 af[4];
#pragma unroll
            for (int kk = 0; kk < 4; ++kk) {
                short8 t;
                t[0] = (short)f2bf(ua[2 * kk].x);     t[1] = (short)f2bf(ua[2 * kk].y);
                t[2] = (short)f2bf(ua[2 * kk].z);     t[3] = (short)f2bf(ua[2 * kk].w);
                t[4] = (short)f2bf(ua[2 * kk + 1].x); t[5] = (short)f2bf(ua[2 * kk + 1].y);
                t[6] = (short)f2bf(ua[2 * kk + 1].z); t[7] = (short)f2bf(ua[2 * kk + 1].w);
                af[kk] = t;
            }

            // batch 2 loads fly under batch-1 MFMAs
            float4 ub[8];
#pragma unroll
            for (int kk = 0; kk < 4; ++kk) {
                ub[2 * kk]     = *(const float4*)(arow + (kk + 4) * 32);
                ub[2 * kk + 1] = *(const float4*)(arow + (kk + 4) * 32 + 4);
            }

            floatx4 acc[8];
#pragma unroll
            for (int c = 0; c < 8; ++c) acc[c] = (floatx4){0.f, 0.f, 0.f, 0.f};

#pragma unroll
            for (int kk = 0; kk < 4; ++kk) {
#pragma unroll
                for (int c = 0; c < 8; ++c) {
                    short8 bfrag = *(const short8*)&Bl[c * 16 + l15][kk * 32 + quad * 8];
                    acc[c] = __builtin_amdgcn_mfma_f32_16x16x32_bf16(af[kk], bfrag, acc[c], 0, 0, 0);
                }
            }

#pragma unroll
            for (int kk = 0; kk < 4; ++kk) {
                short8 t;
                t[0] = (short)f2bf(ub[2 * kk].x);     t[1] = (short)f2bf(ub[2 * kk].y);
                t[2] = (short)f2bf(ub[2 * kk].z);     t[3] = (short)f2bf(ub[2 * kk].w);
                t[4] = (short)f2bf(ub[2 * kk + 1].x); t[5] = (short)f2bf(ub[2 * kk + 1].y);
                t[6] = (short)f2bf(ub[2 * kk + 1].z); t[7] = (short)f2bf(ub[2 * kk + 1].w);
                af[kk] = t;
            }
#pragma unroll
            for (int kk = 0; kk < 4; ++kk) {
#pragma unroll
                for (int c = 0; c < 8; ++c) {
                    short8 bfrag = *(const short8*)&Bl[c * 16 + l15][(kk + 4) * 32 + quad * 8];
                    acc[c] = __builtin_amdgcn_mfma_f32_16x16x32_bf16(af[kk], bfrag, acc[c], 0, 0, 0);
                }
            }

            // ---- C write (bf16) ----
#pragma unroll
            for (int c = 0; c < 8; ++c) {
                const int col = half * 128 + c * 16 + l15;
#pragma unroll
                for (int r = 0; r < 4; ++r) {
                    const int m = g * 16 + quad * 4 + r;
                    C[(size_t)m * NCOL + col] = f2bf(acc[c][r]);
                }
            }

            // ---- fused dots for the 2 heads in this half ----
            float p1[2][4] = {{0.f,0.f,0.f,0.f},{0.f,0.f,0.f,0.f}};
            float p2[2][4] = {{0.f,0.f,0.f,0.f},{0.f,0.f,0.f,0.f}};
#pragma unroll
            for (int c = 0; c < 8; ++c) {
                const int hl = c >> 2;
                const int hh = half * 2 + hl;
                const int jj = (c & 3) * 16 + l15;
                const float w1 = a1[hh * 128 + off_aj + jj];
                const float w2 = a2[hh * 128 + off_aj + jj];
#pragma unroll
                for (int r = 0; r < 4; ++r) {
                    p1[hl][r] += acc[c][r] * w1;
                    p2[hl][r] += acc[c][r] * w2;
                }
            }
#pragma unroll
            for (int m = 1; m < 16; m <<= 1) {
#pragma unroll
                for (int hl = 0; hl < 2; ++hl)
#pragma unroll
                    for (int r = 0; r < 4; ++r) {
                        p1[hl][r] += __shfl_xor(p1[hl][r], m, 64);
                        p2[hl][r] += __shfl_xor(p2[hl][r], m, 64);
                    }
            }
            if (l15 == 0) {
#pragma unroll
                for (int r = 0; r < 4; ++r) {
                    const int m = g * 16 + quad * 4 + r;
#pragma unroll
                    for (int hl = 0; hl < 2; ++hl) {
                        const int hh = half * 2 + hl;
                        o1[m * HEADS + hh] = p1[hl][r];
                        o2[m * HEADS + hh] = p2[hl][r];
                    }
                }
            }
        }
    }

    grid.sync();

    // ---------------- P2: aggregation (round-1/5 verified body) ------------
    {
        const int dir = blk & 1;             // = XCD parity
        const int bi2 = blk >> 1;            // 0..255
        const int wave = tid >> 6;
        const int lane = tid & 63;
        const int h    = lane >> 4;
        const int coff = lane * 4;

        const int*            cnt   = dir ? cnt_s   : cnt_t;
        const unsigned short* list  = dir ? elist_s : elist_t;
        const unsigned short* table = dir ? C1      : C0;    // t_bf : s_bf
        const float*          nsc   = dir ? ss2     : tt1;
        const float*          esc   = dir ? tt2     : ss1;
        float*                outp  = dir ? h_st    : h_ts;

        const int nstart = (bi2 * N_NODES) >> 8;
        const int nend   = ((bi2 + 1) * N_NODES) >> 8;

        for (int n = nstart + wave; n < nend; n += 8) {
            const float base = nsc[n * HEADS + h];
            int deg = cnt[n];
            if (deg > ELL_CAP) deg = ELL_CAP;
            const int b0 = n * ELL_CAP, b1 = b0 + deg;

            float4 acc = make_float4(0.f, 0.f, 0.f, 0.f);
            float den = 0.f;

            int p = b0;
            for (; p + 3 < b1; p += 4) {
                int m0 = list[p],     m1 = list[p + 1];
                int m2 = list[p + 2], m3 = list[p + 3];
                float e0 = esc[m0 * HEADS + h], e1 = esc[m1 * HEADS + h];
                float e2 = esc[m2 * HEADS + h], e3 = esc[m3 * HEADS + h];
                ushort4 r0 = *(const ushort4*)(table + (size_t)m0 * NCOL + coff);
                ushort4 r1 = *(const ushort4*)(table + (size_t)m1 * NCOL + coff);
                ushort4 r2 = *(const ushort4*)(table + (size_t)m2 * NCOL + coff);
                ushort4 r3 = *(const ushort4*)(table + (size_t)m3 * NCOL + coff);
                float w0 = __expf(lrelu(e0 + base));
                float w1 = __expf(lrelu(e1 + base));
                float w2 = __expf(lrelu(e2 + base));
                float w3 = __expf(lrelu(e3 + base));
                den += (w0 + w1) + (w2 + w3);
                acc.x += (w0 * bf2f(r0.x) + w1 * bf2f(r1.x)) + (w2 * bf2f(r2.x) + w3 * bf2f(r3.x));
                acc.y += (w0 * bf2f(r0.y) + w1 * bf2f(r1.y)) + (w2 * bf2f(r2.y) + w3 * bf2f(r3.y));
                acc.z += (w0 * bf2f(r0.z) + w1 * bf2f(r1.z)) + (w2 * bf2f(r2.z) + w3 * bf2f(r3.z));
                acc.w += (w0 * bf2f(r0.w) + w1 * bf2f(r1.w)) + (w2 * bf2f(r2.w) + w3 * bf2f(r3.w));
            }
            for (; p < b1; ++p) {
                int m0 = list[p];
                float w0 = __expf(lrelu(esc[m0 * HEADS + h] + base));
                ushort4 r0 = *(const ushort4*)(table + (size_t)m0 * NCOL + coff);
                den += w0;
                acc.x += w0 * bf2f(r0.x);
                acc.y += w0 * bf2f(r0.y);
                acc.z += w0 * bf2f(r0.z);
                acc.w += w0 * bf2f(r0.w);
            }

            if (den == 0.f) den = 1.f;
            float inv = 1.f / den;
            float4 r;
            r.x = acc.x * inv; r.y = acc.y * inv; r.z = acc.z * inv; r.w = acc.w * inv;
            r.x = (r.x > 0.f) ? r.x : expm1f(r.x);
            r.y = (r.y > 0.f) ? r.y : expm1f(r.y);
            r.z = (r.z > 0.f) ? r.z : expm1f(r.z);
            r.w = (r.w > 0.f) ? r.w : expm1f(r.w);
            *(float4*)(outp + (size_t)n * NCOL + coff) = r;
        }
    }
}

// ===========================================================================
// FALLBACK: round-5 verified 3-dispatch path (used only if the cooperative
// launch is rejected synchronously).
// ===========================================================================
__global__ __launch_bounds__(256) void prep_w_kernel(
    const float* __restrict__ Ws, const float* __restrict__ Wt,
    unsigned short* __restrict__ Wsb, unsigned short* __restrict__ Wtb,
    int* __restrict__ cnt)
{
    const int gid = blockIdx.x * 256 + threadIdx.x;
    for (int i = gid; i < 2 * N_NODES; i += 16384) cnt[i] = 0;
    const int mat = gid >> 13;
    const int r   = gid & 8191;
    const int kc  = r >> 8;
    const int c   = r & 255;
    const float* W    = mat ? Wt : Ws;
    unsigned short* O = mat ? Wtb : Wsb;
    const int h = c >> 6, j = c & 63;
    const int k0 = kc * 8;
    unsigned short v[8] __attribute__((aligned(16)));
#pragma unroll
    for (int i = 0; i < 8; ++i)
        v[i] = f2bf(W[(size_t)h * (IN_F * OUT_F) + (size_t)(k0 + i) * OUT_F + j]);
    *(uint4*)(O + (size_t)c * IN_F + k0) = *(const uint4*)v;
}

__global__ __launch_bounds__(512, 4) void hybrid_kernel(
    const float* __restrict__ A0, const unsigned short* __restrict__ Wb0,
    const float* __restrict__ A1, const unsigned short* __restrict__ Wb1,
    unsigned short* __restrict__ C0, unsigned short* __restrict__ C1,
    const float* __restrict__ a1, const float* __restrict__ a2,
    float* __restrict__ ss1, float* __restrict__ ss2,
    float* __restrict__ tt1, float* __restrict__ tt2,
    const int* __restrict__ src, const int* __restrict__ tgt,
    int* __restrict__ cnt_t, int* __restrict__ cnt_s,
    unsigned short* __restrict__ elist_t, unsigned short* __restrict__ elist_s)
{
    const int tid = threadIdx.x;
    __shared__ __align__(16) unsigned short Bl[128][264];

    if (blockIdx.x < SCAT_X) {
        const int e = ((int)blockIdx.y * SCAT_X + (int)blockIdx.x) * 512 + tid;
        if (e < N_EDGES) {
            const int s = src[e], t = tgt[e];
            const int p = atomicAdd(&cnt_t[t], 1);
            const int q = atomicAdd(&cnt_s[s], 1);
            if (p < ELL_CAP) elist_t[t * ELL_CAP + p] = (unsigned short)s;
            if (q < ELL_CAP) elist_s[s * ELL_CAP + q] = (unsigned short)t;
        }
        return;
    }

    const int gx   = blockIdx.x - SCAT_X;
    const int half = gx & 1;
    const int gb   = gx >> 1;
    const float* A           = (blockIdx.y == 0) ? A0 : A1;
    const unsigned short* Wb = (blockIdx.y == 0) ? Wb0 : Wb1;
    unsigned short* C        = (blockIdx.y == 0) ? C0 : C1;

    for (int i = tid; i < 4096; i += 512) {
        const int n  = i >> 5;
        const int kc = (i & 31) << 3;
        *(uint4*)&Bl[n][kc] = *(const uint4*)(Wb + (size_t)(half * 128 + n) * IN_F + kc);
    }
    __syncthreads();

    const int lane = tid & 63;
    const int w    = tid >> 6;
    const int quad = lane >> 4;
    const int l15  = lane & 15;
    const int g    = gb * 8 + w;
    if (g >= 1250) return;

    const float* arow = A + (size_t)(g * 16 + l15) * IN_F + quad * 8;

    float4 ua[8];
#pragma unroll
    for (int kk = 0; kk < 4; ++kk) {
        ua[2 * kk]     = *(const float4*)(arow + kk * 32);
        ua[2 * kk + 1] = *(const float4*)(arow + kk * 32 + 4);
    }
    short8 af[4];
#pragma unroll
    for (int kk = 0; kk < 4; ++kk) {
        short8 t;
        t[0] = (short)f2bf(ua[2 * kk].x);     t[1] = (short)f2bf(ua[2 * kk].y);
        t[2] = (short)f2bf(ua[2 * kk].z);     t[3] = (short)f2bf(ua[2 * kk].w);
        t[4] = (short)f2bf(ua[2 * kk + 1].x); t[5] = (short)f2bf(ua[2 * kk + 1].y);
        t[6] = (short)f2bf(ua[2 * kk + 1].z); t[7] = (short)f2bf(ua[2 * kk + 1].w);
        af[kk] = t;
    }
    float4 ub[8];
#pragma unroll
    for (int kk = 0; kk < 4; ++kk) {
        ub[2 * kk]     = *(const float4*)(arow + (kk + 4) * 32);
        ub[2 * kk + 1] = *(const float4*)(arow + (kk + 4) * 32 + 4);
    }
    floatx4 acc[8];
#pragma unroll
    for (int c = 0; c < 8; ++c) acc[c] = (floatx4){0.f, 0.f, 0.f, 0.f};
#pragma unroll
    for (int kk = 0; kk < 4; ++kk)
#pragma unroll
        for (int c = 0; c < 8; ++c) {
            short8 bfrag = *(const short8*)&Bl[c * 16 + l15][kk * 32 + quad * 8];
            acc[c] = __builtin_amdgcn_mfma_f32_16x16x32_bf16(af[kk], bfrag, acc[c], 0, 0, 0);
        }
#pragma unroll
    for (int kk = 0; kk < 4; ++kk) {
        short8 t;
        t[0] = (short)f2bf(ub[2 * kk].x);     t[1] = (short)f2bf(ub[2 * kk].y);
        t[2] = (short)f2bf(ub[2 * kk].z);     t[3] = (short)f2bf(ub[2 * kk].w);
        t[4] = (short)f2bf(ub[2 * kk + 1].x); t[5] = (short)f2bf(ub[2 * kk + 1].y);
        t[6] = (short)f2bf(ub[2 * kk + 1].z); t[7] = (short)f2bf(ub[2 * kk + 1].w);
        af[kk] = t;
    }
#pragma unroll
    for (int kk = 0; kk < 4; ++kk)
#pragma unroll
        for (int c = 0; c < 8; ++c) {
            short8 bfrag = *(const short8*)&Bl[c * 16 + l15][(kk + 4) * 32 + quad * 8];
            acc[c] = __builtin_amdgcn_mfma_f32_16x16x32_bf16(af[kk], bfrag, acc[c], 0, 0, 0);
        }
#pragma unroll
    for (int c = 0; c < 8; ++c) {
        const int col = half * 128 + c * 16 + l15;
#pragma unroll
        for (int r = 0; r < 4; ++r) {
            const int m = g * 16 + quad * 4 + r;
            C[(size_t)m * NCOL + col] = f2bf(acc[c][r]);
        }
    }
    const int off_aj = (blockIdx.y == 0) ? 0 : 64;
    float* o1 = (blockIdx.y == 0) ? ss1 : tt1;
    float* o2 = (blockIdx.y == 0) ? ss2 : tt2;
    float p1[2][4] = {{0.f,0.f,0.f,0.f},{0.f,0.f,0.f,0.f}};
    float p2[2][4] = {{0.f,0.f,0.f,0.f},{0.f,0.f,0.f,0.f}};
#pragma unroll
    for (int c = 0; c < 8; ++c) {
        const int hl = c >> 2;
        const int hh = half * 2 + hl;
        const int jj = (c & 3) * 16 + l15;
        const float w1 = a1[hh * 128 + off_aj + jj];
        const float w2 = a2[hh * 128 + off_aj + jj];
#pragma unroll
        for (int r = 0; r < 4; ++r) {
            p1[hl][r] += acc[c][r] * w1;
            p2[hl][r] += acc[c][r] * w2;
        }
    }
#pragma unroll
    for (int m = 1; m < 16; m <<= 1)
#pragma unroll
        for (int hl = 0; hl < 2; ++hl)
#pragma unroll
            for (int r = 0; r < 4; ++r) {
                p1[hl][r] += __shfl_xor(p1[hl][r], m, 64);
                p2[hl][r] += __shfl_xor(p2[hl][r], m, 64);
            }
    if (l15 == 0) {
#pragma unroll
        for (int r = 0; r < 4; ++r) {
            const int m = g * 16 + quad * 4 + r;
#pragma unroll
            for (int hl = 0; hl < 2; ++hl) {
                const int hh = half * 2 + hl;
                o1[m * HEADS + hh] = p1[hl][r];
                o2[m * HEADS + hh] = p2[hl][r];
            }
        }
    }
}

__global__ __launch_bounds__(256) void agg_kernel(
    const int* __restrict__ cnt_t, const unsigned short* __restrict__ elist_t,
    const int* __restrict__ cnt_s, const unsigned short* __restrict__ elist_s,
    const float* __restrict__ ss1, const float* __restrict__ ss2,
    const float* __restrict__ tt1, const float* __restrict__ tt2,
    const unsigned short* __restrict__ s_bf, const unsigned short* __restrict__ t_bf,
    float* __restrict__ h_st, float* __restrict__ h_ts)
{
    const int b    = blockIdx.x;
    const int dir  = b & 1;
    const int wave = threadIdx.x >> 6;
    const int lane = threadIdx.x & 63;
    const int n    = (b >> 1) * 4 + wave;
    const int h    = lane >> 4;
    const int coff = lane * 4;

    const int*            cnt   = dir ? cnt_s   : cnt_t;
    const unsigned short* list  = dir ? elist_s : elist_t;
    const unsigned short* table = dir ? t_bf    : s_bf;
    const float*          nsc   = dir ? ss2     : tt1;
    const float*          esc   = dir ? tt2     : ss1;
    float*                outp  = dir ? h_st    : h_ts;

    const float base = nsc[n * HEADS + h];
    int deg = cnt[n];
    if (deg > ELL_CAP) deg = ELL_CAP;
    const int b0 = n * ELL_CAP, b1 = b0 + deg;

    float4 acc = make_float4(0.f, 0.f, 0.f, 0.f);
    float den = 0.f;
    int p = b0;
    for (; p + 3 < b1; p += 4) {
        int m0 = list[p],     m1 = list[p + 1];
        int m2 = list[p + 2], m3 = list[p + 3];
        float e0 = esc[m0 * HEADS + h], e1 = esc[m1 * HEADS + h];
        float e2 = esc[m2 * HEADS + h], e3 = esc[m3 * HEADS + h];
        ushort4 r0 = *(const ushort4*)(table + (size_t)m0 * NCOL + coff);
        ushort4 r1 = *(const ushort4*)(table + (size_t)m1 * NCOL + coff);
        ushort4 r2 = *(const ushort4*)(table + (size_t)m2 * NCOL + coff);
        ushort4 r3 = *(const ushort4*)(table + (size_t)m3 * NCOL + coff);
        float w0 = __expf(lrelu(e0 + base));
        float w1 = __expf(lrelu(e1 + base));
        float w2 = __expf(lrelu(e2 + base));
        float w3 = __expf(lrelu(e3 + base));
        den += (w0 + w1) + (w2 + w3);
        acc.x += (w0 * bf2f(r0.x) + w1 * bf2f(r1.x)) + (w2 * bf2f(r2.x) + w3 * bf2f(r3.x));
        acc.y += (w0 * bf2f(r0.y) + w1 * bf2f(r1.y)) + (w2 * bf2f(r2.y) + w3 * bf2f(r3.y));
        acc.z += (w0 * bf2f(r0.z) + w1 * bf2f(r1.z)) + (w2 * bf2f(r2.z) + w3 * bf2f(r3.z));
        acc.w += (w0 * bf2f(r0.w) + w1 * bf2f(r1.w)) + (w2 * bf2f(r2.w) + w3 * bf2f(r3.w));
    }
    for (; p < b1; ++p) {
        int m0 = list[p];
        float w0 = __expf(lrelu(esc[m0 * HEADS + h] + base));
        ushort4 r0 = *(const ushort4*)(table + (size_t)m0 * NCOL + coff);
        den += w0;
        acc.x += w0 * bf2f(r0.x);
        acc.y += w0 * bf2f(r0.y);
        acc.z += w0 * bf2f(r0.z);
        acc.w += w0 * bf2f(r0.w);
    }
    if (den == 0.f) den = 1.f;
    float inv = 1.f / den;
    float4 r;
    r.x = acc.x * inv; r.y = acc.y * inv; r.z = acc.z * inv; r.w = acc.w * inv;
    r.x = (r.x > 0.f) ? r.x : expm1f(r.x);
    r.y = (r.y > 0.f) ? r.y : expm1f(r.y);
    r.z = (r.z > 0.f) ? r.z : expm1f(r.z);
    r.w = (r.w > 0.f) ? r.w : expm1f(r.w);
    *(float4*)(outp + (size_t)n * NCOL + coff) = r;
}

extern "C" void kernel_launch(void* const* d_in, const int* in_sizes, int n_in,
                              void* d_out, int out_size, void* d_ws, size_t ws_size,
                              hipStream_t stream)
{
    const float* input1 = (const float*)d_in[0];
    const float* input2 = (const float*)d_in[1];
    const float* Ws     = (const float*)d_in[2];
    const float* Wt     = (const float*)d_in[3];
    const float* a1     = (const float*)d_in[4];
    const float* a2     = (const float*)d_in[5];
    const int*   tgt    = (const int*)d_in[6];   // tgt_idx precedes src_idx
    const int*   src    = (const int*)d_in[7];

    float* out  = (float*)d_out;
    float* h_st = out;                            // [N, 256]
    float* h_ts = out + (size_t)N_NODES * NCOL;   // [N, 256]

    // workspace layout (~27.3 MB)
    unsigned short* s_bf = (unsigned short*)d_ws;             // 5,120,000 bf16
    unsigned short* t_bf = s_bf + (size_t)N_NODES * NCOL;     // 5,120,000 bf16
    unsigned short* Wsb  = t_bf + (size_t)N_NODES * NCOL;     // 65,536 bf16
    unsigned short* Wtb  = Wsb + 256 * 256;                   // 65,536 bf16
    float* ss1  = (float*)(Wtb + 256 * 256);                  // 80,000 f each
    float* ss2  = ss1 + N_NODES * HEADS;
    float* tt1  = ss2 + N_NODES * HEADS;
    float* tt2  = tt1 + N_NODES * HEADS;
    int*   cnt_t = (int*)(tt2 + N_NODES * HEADS);             // 20000
    int*   cnt_s = cnt_t + N_NODES;                           // 20000
    unsigned short* elist_t = (unsigned short*)(cnt_s + N_NODES);   // 20000*64 us
    unsigned short* elist_s = elist_t + (size_t)N_NODES * ELL_CAP;  // 20000*64 us

    // single cooperative dispatch
    void* args[] = {
        (void*)&input1, (void*)&input2, (void*)&Ws, (void*)&Wt,
        (void*)&a1, (void*)&a2, (void*)&src, (void*)&tgt,
        (void*)&Wsb, (void*)&Wtb, (void*)&s_bf, (void*)&t_bf,
        (void*)&ss1, (void*)&ss2, (void*)&tt1, (void*)&tt2,
        (void*)&cnt_t, (void*)&cnt_s, (void*)&elist_t, (void*)&elist_s,
        (void*)&h_st, (void*)&h_ts
    };
    hipError_t err = hipLaunchCooperativeKernel(
        (const void*)fused_kernel, dim3(FUSED_BLOCKS), dim3(FUSED_THREADS),
        args, 0, stream);

    if (err != hipSuccess) {
        // fallback: round-5 verified 3-dispatch path
        prep_w_kernel<<<64, 256, 0, stream>>>(Ws, Wt, Wsb, Wtb, cnt_t);
        dim3 ggrid(SCAT_X + GEMM_GB * 2, 2);
        hybrid_kernel<<<ggrid, 512, 0, stream>>>(input1, Wsb, input2, Wtb,
                                                 s_bf, t_bf, a1, a2,
                                                 ss1, ss2, tt1, tt2,
                                                 src, tgt, cnt_t, cnt_s,
                                                 elist_t, elist_s);
        agg_kernel<<<10000, 256, 0, stream>>>(cnt_t, elist_t, cnt_s, elist_s,
                                              ss1, ss2, tt1, tt2, s_bf, t_bf,
                                              h_st, h_ts);
    }
}

// Round 7
// 190.474 us; speedup vs baseline: 2.4609x; 2.4609x over previous
//
#include <hip/hip_runtime.h>
#include <math.h>

#define N_NODES 20000
#define N_EDGES 320000
#define IN_F 256
#define OUT_F 64
#define HEADS 4
#define NCOL 256            // HEADS*OUT_F
#define LRELU_ALPHA 0.1f
#define ELL_CAP 64          // max degree capacity; P(overflow) < 1e-13

#define SCAT_X 313                         // scatter blocks per y (512 thr, 1 edge/thread)
#define GEMM_X 158                         // 79 blocks x 2 halves; 2 row-groups per wave

typedef __attribute__((ext_vector_type(8))) short short8;
typedef __attribute__((ext_vector_type(4))) float floatx4;

__device__ __forceinline__ float lrelu(float x) {
    return x > 0.f ? x : LRELU_ALPHA * x;
}
__device__ __forceinline__ unsigned short f2bf(float f) {   // RNE f32->bf16
    unsigned int u = __float_as_uint(f);
    u = (u + 0x7FFF + ((u >> 16) & 1)) >> 16;
    return (unsigned short)u;
}
__device__ __forceinline__ float bf2f(unsigned short u) {
    return __uint_as_float(((unsigned int)u) << 16);
}

// ---------------------------------------------------------------------------
// prep_w (64 blocks x 256): W[h][k][j] f32 -> Wb[c][k] bf16 (c=h*64+j,
// k contiguous) AND zero the 2*N_NODES ELL counters.  [verified r0-r5]
// ---------------------------------------------------------------------------
__global__ __launch_bounds__(256) void prep_w_kernel(
    const float* __restrict__ Ws, const float* __restrict__ Wt,
    unsigned short* __restrict__ Wsb, unsigned short* __restrict__ Wtb,
    int* __restrict__ cnt)   // cnt_t followed by cnt_s
{
    const int gid = blockIdx.x * 256 + threadIdx.x;   // [0, 16384)

    for (int i = gid; i < 2 * N_NODES; i += 16384) cnt[i] = 0;

    const int mat = gid >> 13;
    const int r   = gid & 8191;
    const int kc  = r >> 8;          // 0..31 (k-octet)
    const int c   = r & 255;
    const float* W    = mat ? Wt : Ws;
    unsigned short* O = mat ? Wtb : Wsb;
    const int h = c >> 6, j = c & 63;
    const int k0 = kc * 8;
    unsigned short v[8] __attribute__((aligned(16)));
#pragma unroll
    for (int i = 0; i < 8; ++i)
        v[i] = f2bf(W[(size_t)h * (IN_F * OUT_F) + (size_t)(k0 + i) * OUT_F + j]);
    *(uint4*)(O + (size_t)c * IN_F + k0) = *(const uint4*)v;
}

// ---------------------------------------------------------------------------
// hybrid: scatter specialists (x < SCAT_X, 1 edge/thread) + half-W-resident
// GEMM + fused dots (x >= SCAT_X). GEMM body = round-5 verified, but each
// wave now covers TWO row-groups (g = gb*16 + gi*8 + w): halves block count
// and Wb restaging, and the 2nd group's A loads overlap the 1st's MFMAs.
// ---------------------------------------------------------------------------
__global__ __launch_bounds__(512, 4) void hybrid_kernel(
    const float* __restrict__ A0, const unsigned short* __restrict__ Wb0,
    const float* __restrict__ A1, const unsigned short* __restrict__ Wb1,
    unsigned short* __restrict__ C0, unsigned short* __restrict__ C1,
    const float* __restrict__ a1, const float* __restrict__ a2,
    float* __restrict__ ss1, float* __restrict__ ss2,
    float* __restrict__ tt1, float* __restrict__ tt2,
    const int* __restrict__ src, const int* __restrict__ tgt,
    int* __restrict__ cnt_t, int* __restrict__ cnt_s,
    unsigned short* __restrict__ elist_t, unsigned short* __restrict__ elist_s)
{
    const int tid = threadIdx.x;

    __shared__ __align__(16) unsigned short Bl[128][264];   // 67,584 B

    if (blockIdx.x < SCAT_X) {
        // ---- scatter: one edge per thread ----
        const int e = ((int)blockIdx.y * SCAT_X + (int)blockIdx.x) * 512 + tid;
        if (e < N_EDGES) {
            const int s = src[e], t = tgt[e];
            const int p = atomicAdd(&cnt_t[t], 1);
            const int q = atomicAdd(&cnt_s[s], 1);
            if (p < ELL_CAP) elist_t[t * ELL_CAP + p] = (unsigned short)s;
            if (q < ELL_CAP) elist_s[s * ELL_CAP + q] = (unsigned short)t;
        }
        return;
    }

    // ---- GEMM + fused dots ----
    const int gx   = blockIdx.x - SCAT_X;   // 0..157
    const int half = gx & 1;
    const int gb   = gx >> 1;               // 0..78
    const float* A           = (blockIdx.y == 0) ? A0 : A1;
    const unsigned short* Wb = (blockIdx.y == 0) ? Wb0 : Wb1;
    unsigned short* C        = (blockIdx.y == 0) ? C0 : C1;

    for (int i = tid; i < 4096; i += 512) {
        const int n  = i >> 5;            // 0..127
        const int kc = (i & 31) << 3;     // k-offset in shorts
        *(uint4*)&Bl[n][kc] = *(const uint4*)(Wb + (size_t)(half * 128 + n) * IN_F + kc);
    }
    __syncthreads();

    const int lane = tid & 63;
    const int w    = tid >> 6;            // wave 0..7
    const int quad = lane >> 4;
    const int l15  = lane & 15;

    const int off_aj = (blockIdx.y == 0) ? 0 : 64;
    float* o1 = (blockIdx.y == 0) ? ss1 : tt1;
    float* o2 = (blockIdx.y == 0) ? ss2 : tt2;

#pragma unroll
    for (int gi = 0; gi < 2; ++gi) {
        const int g = gb * 16 + gi * 8 + w;   // row group
        if (g >= 1250) continue;

        const float* arow = A + (size_t)(g * 16 + l15) * IN_F + quad * 8;

        // batch 1: kk = 0..3
        float4 ua[8];
#pragma unroll
        for (int kk = 0; kk < 4; ++kk) {
            ua[2 * kk]     = *(const float4*)(arow + kk * 32);
            ua[2 * kk + 1] = *(const float4*)(arow + kk * 32 + 4);
        }
        short8 af[4];
#pragma unroll
        for (int kk = 0; kk < 4; ++kk) {
            short8 t;
            t[0] = (short)f2bf(ua[2 * kk].x);     t[1] = (short)f2bf(ua[2 * kk].y);
            t[2] = (short)f2bf(ua[2 * kk].z);     t[3] = (short)f2bf(ua[2 * kk].w);
            t[4] = (short)f2bf(ua[2 * kk + 1].x); t[5] = (short)f2bf(ua[2 * kk + 1].y);
            t[6] = (short)f2bf(ua[2 * kk + 1].z); t[7] = (short)f2bf(ua[2 * kk + 1].w);
            af[kk] = t;
        }

        // batch 2 loads fly under batch-1 MFMAs
        float4 ub[8];
#pragma unroll
        for (int kk = 0; kk < 4; ++kk) {
            ub[2 * kk]     = *(const float4*)(arow + (kk + 4) * 32);
            ub[2 * kk + 1] = *(const float4*)(arow + (kk + 4) * 32 + 4);
        }

        floatx4 acc[8];
#pragma unroll
        for (int c = 0; c < 8; ++c) acc[c] = (floatx4){0.f, 0.f, 0.f, 0.f};

#pragma unroll
        for (int kk = 0; kk < 4; ++kk) {
#pragma unroll
            for (int c = 0; c < 8; ++c) {
                short8 bfrag = *(const short8*)&Bl[c * 16 + l15][kk * 32 + quad * 8];
                acc[c] = __builtin_amdgcn_mfma_f32_16x16x32_bf16(af[kk], bfrag, acc[c], 0, 0, 0);
            }
        }

#pragma unroll
        for (int kk = 0; kk < 4; ++kk) {
            short8 t;
            t[0] = (short)f2bf(ub[2 * kk].x);     t[1] = (short)f2bf(ub[2 * kk].y);
            t[2] = (short)f2bf(ub[2 * kk].z);     t[3] = (short)f2bf(ub[2 * kk].w);
            t[4] = (short)f2bf(ub[2 * kk + 1].x); t[5] = (short)f2bf(ub[2 * kk + 1].y);
            t[6] = (short)f2bf(ub[2 * kk + 1].z); t[7] = (short)f2bf(ub[2 * kk + 1].w);
            af[kk] = t;
        }
#pragma unroll
        for (int kk = 0; kk < 4; ++kk) {
#pragma unroll
            for (int c = 0; c < 8; ++c) {
                short8 bfrag = *(const short8*)&Bl[c * 16 + l15][(kk + 4) * 32 + quad * 8];
                acc[c] = __builtin_amdgcn_mfma_f32_16x16x32_bf16(af[kk], bfrag, acc[c], 0, 0, 0);
            }
        }

        // ---- C write (bf16) ----
#pragma unroll
        for (int c = 0; c < 8; ++c) {
            const int col = half * 128 + c * 16 + l15;
#pragma unroll
            for (int r = 0; r < 4; ++r) {
                const int m = g * 16 + quad * 4 + r;
                C[(size_t)m * NCOL + col] = f2bf(acc[c][r]);
            }
        }

        // ---- fused dots for the 2 heads in this half ----
        float p1[2][4] = {{0.f,0.f,0.f,0.f},{0.f,0.f,0.f,0.f}};
        float p2[2][4] = {{0.f,0.f,0.f,0.f},{0.f,0.f,0.f,0.f}};
#pragma unroll
        for (int c = 0; c < 8; ++c) {
            const int hl = c >> 2;                       // local head 0..1
            const int hh = half * 2 + hl;
            const int jj = (c & 3) * 16 + l15;
            const float w1 = a1[hh * 128 + off_aj + jj];
            const float w2 = a2[hh * 128 + off_aj + jj];
#pragma unroll
            for (int r = 0; r < 4; ++r) {
                p1[hl][r] += acc[c][r] * w1;
                p2[hl][r] += acc[c][r] * w2;
            }
        }
#pragma unroll
        for (int m = 1; m < 16; m <<= 1) {
#pragma unroll
            for (int hl = 0; hl < 2; ++hl)
#pragma unroll
                for (int r = 0; r < 4; ++r) {
                    p1[hl][r] += __shfl_xor(p1[hl][r], m, 64);
                    p2[hl][r] += __shfl_xor(p2[hl][r], m, 64);
                }
        }
        if (l15 == 0) {
#pragma unroll
            for (int r = 0; r < 4; ++r) {
                const int m = g * 16 + quad * 4 + r;
#pragma unroll
                for (int hl = 0; hl < 2; ++hl) {
                    const int hh = half * 2 + hl;
                    o1[m * HEADS + hh] = p1[hl][r];
                    o2[m * HEADS + hh] = p2[hl][r];
                }
            }
        }
    }
}

// ---------------------------------------------------------------------------
// agg: round-1/5 verified body (wave-per-node, full 256-col row per wave,
// 1 exp per edge-head, dir = blockIdx.x & 1). Changes: 8-edge main unroll
// (16 outstanding gathers/wave, 2x round-1's ILP) and broadcast ushort4
// loads of the edge list (1 instr per 4 entries instead of 4).
// ---------------------------------------------------------------------------
__global__ __launch_bounds__(256) void agg_kernel(
    const int* __restrict__ cnt_t, const unsigned short* __restrict__ elist_t,
    const int* __restrict__ cnt_s, const unsigned short* __restrict__ elist_s,
    const float* __restrict__ ss1, const float* __restrict__ ss2,
    const float* __restrict__ tt1, const float* __restrict__ tt2,
    const unsigned short* __restrict__ s_bf, const unsigned short* __restrict__ t_bf,
    float* __restrict__ h_st, float* __restrict__ h_ts)
{
    const int b    = blockIdx.x;            // 0..9999
    const int dir  = b & 1;                 // = XCD parity
    const int wave = threadIdx.x >> 6;
    const int lane = threadIdx.x & 63;
    const int n    = (b >> 1) * 4 + wave;   // 5000*4 == 20000
    const int h    = lane >> 4;
    const int coff = lane * 4;

    const int*            cnt   = dir ? cnt_s   : cnt_t;
    const unsigned short* list  = dir ? elist_s : elist_t;
    const unsigned short* table = dir ? t_bf    : s_bf;
    const float*          nsc   = dir ? ss2     : tt1;
    const float*          esc   = dir ? tt2     : ss1;
    float*                outp  = dir ? h_st    : h_ts;

    const float base = nsc[n * HEADS + h];
    int deg = cnt[n];
    if (deg > ELL_CAP) deg = ELL_CAP;
    const int b0 = n * ELL_CAP, b1 = b0 + deg;

    float4 acc = make_float4(0.f, 0.f, 0.f, 0.f);
    float den = 0.f;

    int p = b0;
    for (; p + 7 < b1; p += 8) {
        ushort4 lv0 = *(const ushort4*)(list + p);
        ushort4 lv1 = *(const ushort4*)(list + p + 4);
        int m0 = lv0.x, m1 = lv0.y, m2 = lv0.z, m3 = lv0.w;
        int m4 = lv1.x, m5 = lv1.y, m6 = lv1.z, m7 = lv1.w;
        float e0 = esc[m0 * HEADS + h], e1 = esc[m1 * HEADS + h];
        float e2 = esc[m2 * HEADS + h], e3 = esc[m3 * HEADS + h];
        float e4 = esc[m4 * HEADS + h], e5 = esc[m5 * HEADS + h];
        float e6 = esc[m6 * HEADS + h], e7 = esc[m7 * HEADS + h];
        ushort4 r0 = *(const ushort4*)(table + (size_t)m0 * NCOL + coff);
        ushort4 r1 = *(const ushort4*)(table + (size_t)m1 * NCOL + coff);
        ushort4 r2 = *(const ushort4*)(table + (size_t)m2 * NCOL + coff);
        ushort4 r3 = *(const ushort4*)(table + (size_t)m3 * NCOL + coff);
        ushort4 r4 = *(const ushort4*)(table + (size_t)m4 * NCOL + coff);
        ushort4 r5 = *(const ushort4*)(table + (size_t)m5 * NCOL + coff);
        ushort4 r6 = *(const ushort4*)(table + (size_t)m6 * NCOL + coff);
        ushort4 r7 = *(const ushort4*)(table + (size_t)m7 * NCOL + coff);
        float w0 = __expf(lrelu(e0 + base));
        float w1 = __expf(lrelu(e1 + base));
        float w2 = __expf(lrelu(e2 + base));
        float w3 = __expf(lrelu(e3 + base));
        float w4 = __expf(lrelu(e4 + base));
        float w5 = __expf(lrelu(e5 + base));
        float w6 = __expf(lrelu(e6 + base));
        float w7 = __expf(lrelu(e7 + base));
        den += ((w0 + w1) + (w2 + w3)) + ((w4 + w5) + (w6 + w7));
        acc.x += ((w0 * bf2f(r0.x) + w1 * bf2f(r1.x)) + (w2 * bf2f(r2.x) + w3 * bf2f(r3.x)))
               + ((w4 * bf2f(r4.x) + w5 * bf2f(r5.x)) + (w6 * bf2f(r6.x) + w7 * bf2f(r7.x)));
        acc.y += ((w0 * bf2f(r0.y) + w1 * bf2f(r1.y)) + (w2 * bf2f(r2.y) + w3 * bf2f(r3.y)))
               + ((w4 * bf2f(r4.y) + w5 * bf2f(r5.y)) + (w6 * bf2f(r6.y) + w7 * bf2f(r7.y)));
        acc.z += ((w0 * bf2f(r0.z) + w1 * bf2f(r1.z)) + (w2 * bf2f(r2.z) + w3 * bf2f(r3.z)))
               + ((w4 * bf2f(r4.z) + w5 * bf2f(r5.z)) + (w6 * bf2f(r6.z) + w7 * bf2f(r7.z)));
        acc.w += ((w0 * bf2f(r0.w) + w1 * bf2f(r1.w)) + (w2 * bf2f(r2.w) + w3 * bf2f(r3.w)))
               + ((w4 * bf2f(r4.w) + w5 * bf2f(r5.w)) + (w6 * bf2f(r6.w) + w7 * bf2f(r7.w)));
    }
    for (; p + 3 < b1; p += 4) {
        ushort4 lv = *(const ushort4*)(list + p);
        int m0 = lv.x, m1 = lv.y, m2 = lv.z, m3 = lv.w;
        float e0 = esc[m0 * HEADS + h], e1 = esc[m1 * HEADS + h];
        float e2 = esc[m2 * HEADS + h], e3 = esc[m3 * HEADS + h];
        ushort4 r0 = *(const ushort4*)(table + (size_t)m0 * NCOL + coff);
        ushort4 r1 = *(const ushort4*)(table + (size_t)m1 * NCOL + coff);
        ushort4 r2 = *(const ushort4*)(table + (size_t)m2 * NCOL + coff);
        ushort4 r3 = *(const ushort4*)(table + (size_t)m3 * NCOL + coff);
        float w0 = __expf(lrelu(e0 + base));
        float w1 = __expf(lrelu(e1 + base));
        float w2 = __expf(lrelu(e2 + base));
        float w3 = __expf(lrelu(e3 + base));
        den += (w0 + w1) + (w2 + w3);
        acc.x += (w0 * bf2f(r0.x) + w1 * bf2f(r1.x)) + (w2 * bf2f(r2.x) + w3 * bf2f(r3.x));
        acc.y += (w0 * bf2f(r0.y) + w1 * bf2f(r1.y)) + (w2 * bf2f(r2.y) + w3 * bf2f(r3.y));
        acc.z += (w0 * bf2f(r0.z) + w1 * bf2f(r1.z)) + (w2 * bf2f(r2.z) + w3 * bf2f(r3.z));
        acc.w += (w0 * bf2f(r0.w) + w1 * bf2f(r1.w)) + (w2 * bf2f(r2.w) + w3 * bf2f(r3.w));
    }
    for (; p < b1; ++p) {
        int m0 = list[p];
        float w0 = __expf(lrelu(esc[m0 * HEADS + h] + base));
        ushort4 r0 = *(const ushort4*)(table + (size_t)m0 * NCOL + coff);
        den += w0;
        acc.x += w0 * bf2f(r0.x);
        acc.y += w0 * bf2f(r0.y);
        acc.z += w0 * bf2f(r0.z);
        acc.w += w0 * bf2f(r0.w);
    }

    if (den == 0.f) den = 1.f;
    float inv = 1.f / den;
    float4 r;
    r.x = acc.x * inv; r.y = acc.y * inv; r.z = acc.z * inv; r.w = acc.w * inv;
    r.x = (r.x > 0.f) ? r.x : expm1f(r.x);
    r.y = (r.y > 0.f) ? r.y : expm1f(r.y);
    r.z = (r.z > 0.f) ? r.z : expm1f(r.z);
    r.w = (r.w > 0.f) ? r.w : expm1f(r.w);
    *(float4*)(outp + (size_t)n * NCOL + coff) = r;
}

extern "C" void kernel_launch(void* const* d_in, const int* in_sizes, int n_in,
                              void* d_out, int out_size, void* d_ws, size_t ws_size,
                              hipStream_t stream)
{
    const float* input1 = (const float*)d_in[0];
    const float* input2 = (const float*)d_in[1];
    const float* Ws     = (const float*)d_in[2];
    const float* Wt     = (const float*)d_in[3];
    const float* a1     = (const float*)d_in[4];
    const float* a2     = (const float*)d_in[5];
    const int*   tgt    = (const int*)d_in[6];   // tgt_idx precedes src_idx
    const int*   src    = (const int*)d_in[7];

    float* out  = (float*)d_out;
    float* h_st = out;                            // [N, 256]
    float* h_ts = out + (size_t)N_NODES * NCOL;   // [N, 256]

    // workspace layout (~27.3 MB)
    unsigned short* s_bf = (unsigned short*)d_ws;             // 5,120,000 bf16
    unsigned short* t_bf = s_bf + (size_t)N_NODES * NCOL;     // 5,120,000 bf16
    unsigned short* Wsb  = t_bf + (size_t)N_NODES * NCOL;     // 65,536 bf16
    unsigned short* Wtb  = Wsb + 256 * 256;                   // 65,536 bf16
    float* ss1  = (float*)(Wtb + 256 * 256);                  // 80,000 f each
    float* ss2  = ss1 + N_NODES * HEADS;
    float* tt1  = ss2 + N_NODES * HEADS;
    float* tt2  = tt1 + N_NODES * HEADS;
    int*   cnt_t = (int*)(tt2 + N_NODES * HEADS);             // 20000
    int*   cnt_s = cnt_t + N_NODES;                           // 20000
    unsigned short* elist_t = (unsigned short*)(cnt_s + N_NODES);   // 20000*64 us
    unsigned short* elist_s = elist_t + (size_t)N_NODES * ELL_CAP;  // 20000*64 us

    // dispatch 1: W convert + counter zeroing
    prep_w_kernel<<<64, 256, 0, stream>>>(Ws, Wt, Wsb, Wtb, cnt_t);

    // dispatch 2: hybrid scatter + GEMM (2 row-groups per wave) + fused dots
    dim3 ggrid(SCAT_X + GEMM_X, 2);
    hybrid_kernel<<<ggrid, 512, 0, stream>>>(input1, Wsb, input2, Wtb,
                                             s_bf, t_bf, a1, a2,
                                             ss1, ss2, tt1, tt2,
                                             src, tgt, cnt_t, cnt_s,
                                             elist_t, elist_s);

    // dispatch 3: dir-parity aggregation, 8-edge unroll
    agg_kernel<<<10000, 256, 0, stream>>>(cnt_t, elist_t, cnt_s, elist_s,
                                          ss1, ss2, tt1, tt2, s_bf, t_bf, h_st, h_ts);
}

// Round 8
// 181.711 us; speedup vs baseline: 2.5796x; 1.0482x over previous
//
#include <hip/hip_runtime.h>
#include <math.h>

#define N_NODES 20000
#define N_EDGES 320000
#define IN_F 256
#define OUT_F 64
#define HEADS 4
#define NCOL 256            // HEADS*OUT_F
#define LRELU_ALPHA 0.1f
#define ELL_CAP 64          // max degree capacity; P(overflow) < 1e-13

#define SCAT_X 313                         // scatter blocks per y (512 thr, 1 edge/thread)
#define GEMM_GB 157                        // ceil(1250 row-groups / 8 waves)
#define CST_STRIDE 136                     // shorts per staged C row (272 B = 17x16, 16B aligned)

typedef __attribute__((ext_vector_type(8))) short short8;
typedef __attribute__((ext_vector_type(4))) float floatx4;

__device__ __forceinline__ float lrelu(float x) {
    return x > 0.f ? x : LRELU_ALPHA * x;
}
__device__ __forceinline__ unsigned short f2bf(float f) {   // RNE f32->bf16
    unsigned int u = __float_as_uint(f);
    u = (u + 0x7FFF + ((u >> 16) & 1)) >> 16;
    return (unsigned short)u;
}
__device__ __forceinline__ float bf2f(unsigned short u) {
    return __uint_as_float(((unsigned int)u) << 16);
}

// ---------------------------------------------------------------------------
// prep_w (64 blocks x 256): W[h][k][j] f32 -> Wb[c][k] bf16 (c=h*64+j,
// k contiguous) AND zero the 2*N_NODES ELL counters.  [verified r0-r5]
// ---------------------------------------------------------------------------
__global__ __launch_bounds__(256) void prep_w_kernel(
    const float* __restrict__ Ws, const float* __restrict__ Wt,
    unsigned short* __restrict__ Wsb, unsigned short* __restrict__ Wtb,
    int* __restrict__ cnt)   // cnt_t followed by cnt_s
{
    const int gid = blockIdx.x * 256 + threadIdx.x;   // [0, 16384)

    for (int i = gid; i < 2 * N_NODES; i += 16384) cnt[i] = 0;

    const int mat = gid >> 13;
    const int r   = gid & 8191;
    const int kc  = r >> 8;          // 0..31 (k-octet)
    const int c   = r & 255;
    const float* W    = mat ? Wt : Ws;
    unsigned short* O = mat ? Wtb : Wsb;
    const int h = c >> 6, j = c & 63;
    const int k0 = kc * 8;
    unsigned short v[8] __attribute__((aligned(16)));
#pragma unroll
    for (int i = 0; i < 8; ++i)
        v[i] = f2bf(W[(size_t)h * (IN_F * OUT_F) + (size_t)(k0 + i) * OUT_F + j]);
    *(uint4*)(O + (size_t)c * IN_F + k0) = *(const uint4*)v;
}

// ---------------------------------------------------------------------------
// hybrid: scatter specialists (x < SCAT_X, 1 edge/thread) + half-W-resident
// GEMM + fused dots (x >= SCAT_X; round-5 verified body). NEW vs r5: the C
// tile (128 rows x 128 cols bf16) is staged in LDS (reusing Bl after a
// barrier) and written out as full 256 B contiguous row-segments -> only
// full-line writebacks, no partial-line RMW (r5 WRITE_SIZE 60 MB vs 27 MB
// payload). Early-return replaced by `live` predicate so all threads reach
// the barriers.
// ---------------------------------------------------------------------------
__global__ __launch_bounds__(512, 4) void hybrid_kernel(
    const float* __restrict__ A0, const unsigned short* __restrict__ Wb0,
    const float* __restrict__ A1, const unsigned short* __restrict__ Wb1,
    unsigned short* __restrict__ C0, unsigned short* __restrict__ C1,
    const float* __restrict__ a1, const float* __restrict__ a2,
    float* __restrict__ ss1, float* __restrict__ ss2,
    float* __restrict__ tt1, float* __restrict__ tt2,
    const int* __restrict__ src, const int* __restrict__ tgt,
    int* __restrict__ cnt_t, int* __restrict__ cnt_s,
    unsigned short* __restrict__ elist_t, unsigned short* __restrict__ elist_s)
{
    const int tid = threadIdx.x;

    __shared__ __align__(16) unsigned short Bl[128][264];   // 67,584 B

    if (blockIdx.x < SCAT_X) {
        // ---- scatter: one edge per thread ----
        const int e = ((int)blockIdx.y * SCAT_X + (int)blockIdx.x) * 512 + tid;
        if (e < N_EDGES) {
            const int s = src[e], t = tgt[e];
            const int p = atomicAdd(&cnt_t[t], 1);
            const int q = atomicAdd(&cnt_s[s], 1);
            if (p < ELL_CAP) elist_t[t * ELL_CAP + p] = (unsigned short)s;
            if (q < ELL_CAP) elist_s[s * ELL_CAP + q] = (unsigned short)t;
        }
        return;
    }

    // ---- GEMM + fused dots (round-5 verified core) ----
    const int gx   = blockIdx.x - SCAT_X;
    const int half = gx & 1;
    const int gb   = gx >> 1;             // 0..156
    const float* A           = (blockIdx.y == 0) ? A0 : A1;
    const unsigned short* Wb = (blockIdx.y == 0) ? Wb0 : Wb1;
    unsigned short* C        = (blockIdx.y == 0) ? C0 : C1;

    for (int i = tid; i < 4096; i += 512) {
        const int n  = i >> 5;            // 0..127
        const int kc = (i & 31) << 3;     // k-offset in shorts
        *(uint4*)&Bl[n][kc] = *(const uint4*)(Wb + (size_t)(half * 128 + n) * IN_F + kc);
    }
    __syncthreads();

    const int lane = tid & 63;
    const int w    = tid >> 6;            // wave 0..7
    const int quad = lane >> 4;
    const int l15  = lane & 15;
    const int g    = gb * 8 + w;          // row group 0..1255
    const bool live = (g < 1250);

    floatx4 acc[8];
#pragma unroll
    for (int c = 0; c < 8; ++c) acc[c] = (floatx4){0.f, 0.f, 0.f, 0.f};

    if (live) {
        const float* arow = A + (size_t)(g * 16 + l15) * IN_F + quad * 8;

        // batch 1: kk = 0..3
        float4 ua[8];
#pragma unroll
        for (int kk = 0; kk < 4; ++kk) {
            ua[2 * kk]     = *(const float4*)(arow + kk * 32);
            ua[2 * kk + 1] = *(const float4*)(arow + kk * 32 + 4);
        }
        short8 af[4];
#pragma unroll
        for (int kk = 0; kk < 4; ++kk) {
            short8 t;
            t[0] = (short)f2bf(ua[2 * kk].x);     t[1] = (short)f2bf(ua[2 * kk].y);
            t[2] = (short)f2bf(ua[2 * kk].z);     t[3] = (short)f2bf(ua[2 * kk].w);
            t[4] = (short)f2bf(ua[2 * kk + 1].x); t[5] = (short)f2bf(ua[2 * kk + 1].y);
            t[6] = (short)f2bf(ua[2 * kk + 1].z); t[7] = (short)f2bf(ua[2 * kk + 1].w);
            af[kk] = t;
        }

        // batch 2 loads fly under batch-1 MFMAs
        float4 ub[8];
#pragma unroll
        for (int kk = 0; kk < 4; ++kk) {
            ub[2 * kk]     = *(const float4*)(arow + (kk + 4) * 32);
            ub[2 * kk + 1] = *(const float4*)(arow + (kk + 4) * 32 + 4);
        }

#pragma unroll
        for (int kk = 0; kk < 4; ++kk) {
#pragma unroll
            for (int c = 0; c < 8; ++c) {
                short8 bfrag = *(const short8*)&Bl[c * 16 + l15][kk * 32 + quad * 8];
                acc[c] = __builtin_amdgcn_mfma_f32_16x16x32_bf16(af[kk], bfrag, acc[c], 0, 0, 0);
            }
        }

#pragma unroll
        for (int kk = 0; kk < 4; ++kk) {
            short8 t;
            t[0] = (short)f2bf(ub[2 * kk].x);     t[1] = (short)f2bf(ub[2 * kk].y);
            t[2] = (short)f2bf(ub[2 * kk].z);     t[3] = (short)f2bf(ub[2 * kk].w);
            t[4] = (short)f2bf(ub[2 * kk + 1].x); t[5] = (short)f2bf(ub[2 * kk + 1].y);
            t[6] = (short)f2bf(ub[2 * kk + 1].z); t[7] = (short)f2bf(ub[2 * kk + 1].w);
            af[kk] = t;
        }
#pragma unroll
        for (int kk = 0; kk < 4; ++kk) {
#pragma unroll
            for (int c = 0; c < 8; ++c) {
                short8 bfrag = *(const short8*)&Bl[c * 16 + l15][(kk + 4) * 32 + quad * 8];
                acc[c] = __builtin_amdgcn_mfma_f32_16x16x32_bf16(af[kk], bfrag, acc[c], 0, 0, 0);
            }
        }

        // ---- fused dots (register-only; before barriers) ----
        const int off_aj = (blockIdx.y == 0) ? 0 : 64;
        float* o1 = (blockIdx.y == 0) ? ss1 : tt1;
        float* o2 = (blockIdx.y == 0) ? ss2 : tt2;

        float p1[2][4] = {{0.f,0.f,0.f,0.f},{0.f,0.f,0.f,0.f}};
        float p2[2][4] = {{0.f,0.f,0.f,0.f},{0.f,0.f,0.f,0.f}};
#pragma unroll
        for (int c = 0; c < 8; ++c) {
            const int hl = c >> 2;                       // local head 0..1
            const int hh = half * 2 + hl;
            const int jj = (c & 3) * 16 + l15;
            const float w1 = a1[hh * 128 + off_aj + jj];
            const float w2 = a2[hh * 128 + off_aj + jj];
#pragma unroll
            for (int r = 0; r < 4; ++r) {
                p1[hl][r] += acc[c][r] * w1;
                p2[hl][r] += acc[c][r] * w2;
            }
        }
#pragma unroll
        for (int m = 1; m < 16; m <<= 1) {
#pragma unroll
            for (int hl = 0; hl < 2; ++hl)
#pragma unroll
                for (int r = 0; r < 4; ++r) {
                    p1[hl][r] += __shfl_xor(p1[hl][r], m, 64);
                    p2[hl][r] += __shfl_xor(p2[hl][r], m, 64);
                }
        }
        if (l15 == 0) {
#pragma unroll
            for (int r = 0; r < 4; ++r) {
                const int m = g * 16 + quad * 4 + r;
#pragma unroll
                for (int hl = 0; hl < 2; ++hl) {
                    const int hh = half * 2 + hl;
                    o1[m * HEADS + hh] = p1[hl][r];
                    o2[m * HEADS + hh] = p2[hl][r];
                }
            }
        }
    }

    // ---- C write via LDS staging: full-line writebacks only ----
    __syncthreads();                       // all waves done reading Bl
    unsigned short* Cst = &Bl[0][0];       // reuse as [128][CST_STRIDE]

    if (live) {
#pragma unroll
        for (int c = 0; c < 8; ++c) {
            const int lc = c * 16 + l15;               // local col 0..127
#pragma unroll
            for (int r = 0; r < 4; ++r) {
                const int lr = w * 16 + quad * 4 + r;  // local row 0..127
                Cst[lr * CST_STRIDE + lc] = f2bf(acc[c][r]);
            }
        }
    }
    __syncthreads();

    // copy out: 4 iters x (512 thr x 16 B); 16 consecutive lanes = 256 B
    // contiguous in C (2 full 128B lines).
    {
        const int cx = tid & 15;           // 16B chunk within 256B row-seg
        const int rbase = tid >> 4;        // 0..31
#pragma unroll
        for (int it = 0; it < 4; ++it) {
            const int lr = it * 32 + rbase;            // 0..127
            const int mrow = gb * 128 + lr;
            if (mrow < N_NODES) {
                uint4 v = *(const uint4*)&Cst[lr * CST_STRIDE + cx * 8];
                *(uint4*)(C + (size_t)mrow * NCOL + half * 128 + cx * 8) = v;
            }
        }
    }
}

// ---------------------------------------------------------------------------
// agg: round-1/5 verified body, byte-identical (wave-per-node, 4-edge
// unroll, ushort ELL, full 256-col row per wave, dir = blockIdx.x & 1).
// ---------------------------------------------------------------------------
__global__ __launch_bounds__(256) void agg_kernel(
    const int* __restrict__ cnt_t, const unsigned short* __restrict__ elist_t,
    const int* __restrict__ cnt_s, const unsigned short* __restrict__ elist_s,
    const float* __restrict__ ss1, const float* __restrict__ ss2,
    const float* __restrict__ tt1, const float* __restrict__ tt2,
    const unsigned short* __restrict__ s_bf, const unsigned short* __restrict__ t_bf,
    float* __restrict__ h_st, float* __restrict__ h_ts)
{
    const int b    = blockIdx.x;            // 0..9999
    const int dir  = b & 1;                 // = XCD parity
    const int wave = threadIdx.x >> 6;
    const int lane = threadIdx.x & 63;
    const int n    = (b >> 1) * 4 + wave;   // 5000*4 == 20000
    const int h    = lane >> 4;
    const int coff = lane * 4;

    const int*            cnt   = dir ? cnt_s   : cnt_t;
    const unsigned short* list  = dir ? elist_s : elist_t;
    const unsigned short* table = dir ? t_bf    : s_bf;
    const float*          nsc   = dir ? ss2     : tt1;
    const float*          esc   = dir ? tt2     : ss1;
    float*                outp  = dir ? h_st    : h_ts;

    const float base = nsc[n * HEADS + h];
    int deg = cnt[n];
    if (deg > ELL_CAP) deg = ELL_CAP;
    const int b0 = n * ELL_CAP, b1 = b0 + deg;

    float4 acc = make_float4(0.f, 0.f, 0.f, 0.f);
    float den = 0.f;

    int p = b0;
    for (; p + 3 < b1; p += 4) {
        int m0 = list[p],     m1 = list[p + 1];
        int m2 = list[p + 2], m3 = list[p + 3];
        float e0 = esc[m0 * HEADS + h], e1 = esc[m1 * HEADS + h];
        float e2 = esc[m2 * HEADS + h], e3 = esc[m3 * HEADS + h];
        ushort4 r0 = *(const ushort4*)(table + (size_t)m0 * NCOL + coff);
        ushort4 r1 = *(const ushort4*)(table + (size_t)m1 * NCOL + coff);
        ushort4 r2 = *(const ushort4*)(table + (size_t)m2 * NCOL + coff);
        ushort4 r3 = *(const ushort4*)(table + (size_t)m3 * NCOL + coff);
        float w0 = __expf(lrelu(e0 + base));
        float w1 = __expf(lrelu(e1 + base));
        float w2 = __expf(lrelu(e2 + base));
        float w3 = __expf(lrelu(e3 + base));
        den += (w0 + w1) + (w2 + w3);
        acc.x += (w0 * bf2f(r0.x) + w1 * bf2f(r1.x)) + (w2 * bf2f(r2.x) + w3 * bf2f(r3.x));
        acc.y += (w0 * bf2f(r0.y) + w1 * bf2f(r1.y)) + (w2 * bf2f(r2.y) + w3 * bf2f(r3.y));
        acc.z += (w0 * bf2f(r0.z) + w1 * bf2f(r1.z)) + (w2 * bf2f(r2.z) + w3 * bf2f(r3.z));
        acc.w += (w0 * bf2f(r0.w) + w1 * bf2f(r1.w)) + (w2 * bf2f(r2.w) + w3 * bf2f(r3.w));
    }
    for (; p < b1; ++p) {
        int m0 = list[p];
        float w0 = __expf(lrelu(esc[m0 * HEADS + h] + base));
        ushort4 r0 = *(const ushort4*)(table + (size_t)m0 * NCOL + coff);
        den += w0;
        acc.x += w0 * bf2f(r0.x);
        acc.y += w0 * bf2f(r0.y);
        acc.z += w0 * bf2f(r0.z);
        acc.w += w0 * bf2f(r0.w);
    }

    if (den == 0.f) den = 1.f;
    float inv = 1.f / den;
    float4 r;
    r.x = acc.x * inv; r.y = acc.y * inv; r.z = acc.z * inv; r.w = acc.w * inv;
    r.x = (r.x > 0.f) ? r.x : expm1f(r.x);
    r.y = (r.y > 0.f) ? r.y : expm1f(r.y);
    r.z = (r.z > 0.f) ? r.z : expm1f(r.z);
    r.w = (r.w > 0.f) ? r.w : expm1f(r.w);
    *(float4*)(outp + (size_t)n * NCOL + coff) = r;
}

extern "C" void kernel_launch(void* const* d_in, const int* in_sizes, int n_in,
                              void* d_out, int out_size, void* d_ws, size_t ws_size,
                              hipStream_t stream)
{
    const float* input1 = (const float*)d_in[0];
    const float* input2 = (const float*)d_in[1];
    const float* Ws     = (const float*)d_in[2];
    const float* Wt     = (const float*)d_in[3];
    const float* a1     = (const float*)d_in[4];
    const float* a2     = (const float*)d_in[5];
    const int*   tgt    = (const int*)d_in[6];   // tgt_idx precedes src_idx
    const int*   src    = (const int*)d_in[7];

    float* out  = (float*)d_out;
    float* h_st = out;                            // [N, 256]
    float* h_ts = out + (size_t)N_NODES * NCOL;   // [N, 256]

    // workspace layout (~27.3 MB)
    unsigned short* s_bf = (unsigned short*)d_ws;             // 5,120,000 bf16
    unsigned short* t_bf = s_bf + (size_t)N_NODES * NCOL;     // 5,120,000 bf16
    unsigned short* Wsb  = t_bf + (size_t)N_NODES * NCOL;     // 65,536 bf16
    unsigned short* Wtb  = Wsb + 256 * 256;                   // 65,536 bf16
    float* ss1  = (float*)(Wtb + 256 * 256);                  // 80,000 f each
    float* ss2  = ss1 + N_NODES * HEADS;
    float* tt1  = ss2 + N_NODES * HEADS;
    float* tt2  = tt1 + N_NODES * HEADS;
    int*   cnt_t = (int*)(tt2 + N_NODES * HEADS);             // 20000
    int*   cnt_s = cnt_t + N_NODES;                           // 20000
    unsigned short* elist_t = (unsigned short*)(cnt_s + N_NODES);   // 20000*64 us
    unsigned short* elist_s = elist_t + (size_t)N_NODES * ELL_CAP;  // 20000*64 us

    // dispatch 1: W convert + counter zeroing
    prep_w_kernel<<<64, 256, 0, stream>>>(Ws, Wt, Wsb, Wtb, cnt_t);

    // dispatch 2: hybrid scatter + GEMM + fused dots (LDS-staged C write)
    dim3 ggrid(SCAT_X + GEMM_GB * 2, 2);
    hybrid_kernel<<<ggrid, 512, 0, stream>>>(input1, Wsb, input2, Wtb,
                                             s_bf, t_bf, a1, a2,
                                             ss1, ss2, tt1, tt2,
                                             src, tgt, cnt_t, cnt_s,
                                             elist_t, elist_s);

    // dispatch 3: dir-parity aggregation (round-1/5 body)
    agg_kernel<<<10000, 256, 0, stream>>>(cnt_t, elist_t, cnt_s, elist_s,
                                          ss1, ss2, tt1, tt2, s_bf, t_bf, h_st, h_ts);
}